// Round 4
// baseline (2203.952 us; speedup 1.0000x reference)
//
#include <hip/hip_runtime.h>
#include <math.h>

namespace {
constexpr int kD   = 512;
constexpr int kN   = 8192;
constexpr int kS   = 1024;
constexpr int kHD  = 64;
constexpr int kFF  = 2048;
constexpr int kSL  = 512;
constexpr int kOUT = 32;
constexpr int kLQ  = 1536;   // fused QKV row stride
}

typedef __bf16 bf16x8 __attribute__((ext_vector_type(8)));
typedef float  f32x4  __attribute__((ext_vector_type(4)));

__device__ inline unsigned short f2bf(float x) {
    unsigned u = __float_as_uint(x);
    return (unsigned short)((u + 0x7FFF + ((u >> 16) & 1)) >> 16);
}
__device__ inline void split2(float x, unsigned short& h, unsigned short& l) {
    unsigned u = __float_as_uint(x);
    unsigned hb = (u + 0x7FFF + ((u >> 16) & 1)) >> 16;
    h = (unsigned short)hb;
    float hf = __uint_as_float(hb << 16);
    l = f2bf(x - hf);
}

// =====================================================================
// 256x256 split-precision MFMA GEMM, 8-phase schedule (T2+T3+T4+T5).
// 8 waves (wave tile 128x64), BK=32 (4 bf16 planes = 64KB/tile), dbuf.
// Per phase: 2 ds_read prefetch (next m-row) || MFMA cluster (12).
// B-frags in registers per K-tile, prefetched at phases 6-7.
// Stage t+1 at phases 0-1; single vmcnt(0) fence at phase 5.
// MODE 0: C fp32. MODE 1: hi/lo planes. MODE 2: cosine-score epilogue.
// =====================================================================
template<int MODE, int RELU, int HAS_BIAS>
__global__ __launch_bounds__(512, 2)
void mgemm256_k(const unsigned short* __restrict__ Ah, const unsigned short* __restrict__ Al,
                const unsigned short* __restrict__ Bh, const unsigned short* __restrict__ Bl,
                const float* __restrict__ bias, float* __restrict__ C,
                unsigned short* __restrict__ Ch, unsigned short* __restrict__ Cl,
                const float* __restrict__ X, const float* __restrict__ XN,
                float* __restrict__ SC,
                int M, int N, int K, float alpha)
{
    (void)M;
    __shared__ uint4 smem4[8192];           // 128 KB
    unsigned char* smem = (unsigned char*)smem4;
    const int tid = threadIdx.x, lane = tid & 63, w = tid >> 6;

    const int gx = gridDim.x;
    int bid = blockIdx.y * gx + blockIdx.x;
    const int nwg = gx * gridDim.y;
    bid = (bid & 7) * (nwg >> 3) + (bid >> 3);
    const int bx = bid % gx, by = bid / gx;
    const int brow = by * 256, bcol = bx * 256;
    const int wr = (w >> 2) * 128, wc = (w & 3) * 64;
    const size_t K2 = (size_t)K * 2;

    // staging: wave w stages plane (w>>1), half (w&1)
    const int pl = w >> 1, hf = w & 1;
    const unsigned short* SP = (pl == 0) ? Ah : (pl == 1) ? Al : (pl == 2) ? Bh : Bl;
    const int rbase = (pl < 2) ? brow : bcol;
    const int cch = ((lane & 3) - ((lane >> 3) & 3)) & 3;   // inverse swizzle on src
    const unsigned char* src0 = (const unsigned char*)SP
        + (size_t)(rbase + hf * 128 + (lane >> 2)) * K2 + (cch << 4);
    const int ldsw0 = (pl << 14) + (hf << 13);

    // fragment read addressing (swizzled slot)
    const int lm = lane & 15, lg = lane >> 4;
    const int sw = ((lg + (lm >> 1)) & 3) << 4;
    const int aoff = (wr + lm) * 64 + sw;
    const int boff = 32768 + (wc + lm) * 64 + sw;

    f32x4 acc[8][4];
#pragma unroll
    for (int i = 0; i < 8; ++i)
#pragma unroll
        for (int j = 0; j < 4; ++j) acc[i][j] = (f32x4)(0.f);

    auto stage4 = [&](int bufo_, int t_, int j0_) {
        const unsigned char* s_ = src0 + (size_t)t_ * 64;
#pragma unroll
        for (int j = 0; j < 4; ++j)
            __builtin_amdgcn_global_load_lds(
                (const __attribute__((address_space(1))) unsigned int*)(s_ + (size_t)(j0_ + j) * 16 * K2),
                (__attribute__((address_space(3))) unsigned int*)(smem + bufo_ + ldsw0 + (j0_ + j) * 1024),
                16, 0, 0);
    };

    const int nt = K >> 5;
    // prologue: stage tile 0 fully into buf0, preload its fragments
    stage4(0, 0, 0); stage4(0, 0, 4);
    asm volatile("s_waitcnt vmcnt(0)" ::: "memory");
    __builtin_amdgcn_s_barrier();

    bf16x8 rBh[4], rBl[4], nBh[4], nBl[4], ah_c, al_c, ah_n, al_n;
#pragma unroll
    for (int n = 0; n < 4; ++n) {
        rBh[n] = *(const bf16x8*)(smem + boff + n * 1024);
        rBl[n] = *(const bf16x8*)(smem + boff + 16384 + n * 1024);
        nBh[n] = rBh[n]; nBl[n] = rBl[n];
    }
    ah_c = *(const bf16x8*)(smem + aoff);
    al_c = *(const bf16x8*)(smem + aoff + 16384);
    ah_n = ah_c; al_n = al_c;

#pragma unroll 1
    for (int t = 0; t < nt; ++t) {
        unsigned char* cb = smem + ((t & 1) << 16);
        unsigned char* nb = smem + (((t + 1) & 1) << 16);
        const bool nl = (t + 1 < nt);
#pragma unroll
        for (int ph = 0; ph < 8; ++ph) {
            if (ph < 7) {
                ah_n = *(const bf16x8*)(cb + aoff + (ph + 1) * 1024);
                al_n = *(const bf16x8*)(cb + aoff + 16384 + (ph + 1) * 1024);
            }
            if (nl) {
                if (ph == 0) stage4(((t + 1) & 1) << 16, t + 1, 0);
                if (ph == 1) stage4(((t + 1) & 1) << 16, t + 1, 4);
                if (ph == 6) {
#pragma unroll
                    for (int n = 0; n < 2; ++n) {
                        nBh[n] = *(const bf16x8*)(nb + boff + n * 1024);
                        nBl[n] = *(const bf16x8*)(nb + boff + 16384 + n * 1024);
                    }
                }
                if (ph == 7) {
#pragma unroll
                    for (int n = 2; n < 4; ++n) {
                        nBh[n] = *(const bf16x8*)(nb + boff + n * 1024);
                        nBl[n] = *(const bf16x8*)(nb + boff + 16384 + n * 1024);
                    }
                    ah_n = *(const bf16x8*)(nb + aoff);
                    al_n = *(const bf16x8*)(nb + aoff + 16384);
                }
            }
            __builtin_amdgcn_sched_barrier(0);
            if (ph == 5 && nl) asm volatile("s_waitcnt vmcnt(0)" ::: "memory");
            __builtin_amdgcn_s_barrier();
            __builtin_amdgcn_sched_barrier(0);
            __builtin_amdgcn_s_setprio(1);
#pragma unroll
            for (int n = 0; n < 4; ++n) {
                acc[ph][n] = __builtin_amdgcn_mfma_f32_16x16x32_bf16(al_c, rBh[n], acc[ph][n], 0, 0, 0);
                acc[ph][n] = __builtin_amdgcn_mfma_f32_16x16x32_bf16(ah_c, rBl[n], acc[ph][n], 0, 0, 0);
                acc[ph][n] = __builtin_amdgcn_mfma_f32_16x16x32_bf16(ah_c, rBh[n], acc[ph][n], 0, 0, 0);
            }
            __builtin_amdgcn_s_setprio(0);
            __builtin_amdgcn_sched_barrier(0);
            __builtin_amdgcn_s_barrier();
            ah_c = ah_n; al_c = al_n;
            if (ph == 7 && nl) {
#pragma unroll
                for (int n = 0; n < 4; ++n) { rBh[n] = nBh[n]; rBl[n] = nBl[n]; }
            }
        }
    }

    if (MODE == 0 || MODE == 1) {
#pragma unroll
        for (int n = 0; n < 4; ++n) {
            const int colg = bcol + wc + n * 16 + lm;
            const float bv = HAS_BIAS ? bias[colg] : 0.f;
#pragma unroll
            for (int m = 0; m < 8; ++m) {
                const int rowb = brow + wr + m * 16 + lg * 4;
#pragma unroll
                for (int r = 0; r < 4; ++r) {
                    float v = alpha * acc[m][n][r] + bv;
                    if (RELU) v = fmaxf(v, 0.f);
                    if (MODE == 0) {
                        C[(size_t)(rowb + r) * N + colg] = v;
                    } else {
                        unsigned short h, l;
                        split2(v, h, l);
                        Ch[(size_t)(rowb + r) * N + colg] = h;
                        Cl[(size_t)(rowb + r) * N + colg] = l;
                    }
                }
            }
        }
    } else {
        float bv[4];
#pragma unroll
        for (int n = 0; n < 4; ++n) bv[n] = bias[bcol + wc + n * 16 + lm];
        const int slot0 = (bcol + wc) >> 5;
#pragma unroll
        for (int m = 0; m < 8; ++m) {
#pragma unroll
            for (int r = 0; r < 4; ++r) {
                const int row = brow + wr + m * 16 + lg * 4 + r;
                const float x0 = X[(size_t)row * kOUT + lm];
                const float x1 = X[(size_t)row * kOUT + 16 + lm];
                const float xn = XN[row];
#pragma unroll
                for (int s = 0; s < 2; ++s) {
                    const float v0 = acc[m][2 * s][r]     + bv[2 * s];
                    const float v1 = acc[m][2 * s + 1][r] + bv[2 * s + 1];
                    float pd = v0 * x0 + v1 * x1;
                    float pn = v0 * v0 + v1 * v1;
                    pd += __shfl_xor(pd, 1); pd += __shfl_xor(pd, 2);
                    pd += __shfl_xor(pd, 4); pd += __shfl_xor(pd, 8);
                    pn += __shfl_xor(pn, 1); pn += __shfl_xor(pn, 2);
                    pn += __shfl_xor(pn, 4); pn += __shfl_xor(pn, 8);
                    if (lm == 0)
                        SC[(size_t)row * kSL + slot0 + s] = pd / (sqrtf(pn) * xn);
                }
            }
        }
    }
}

// =====================================================================
// 128x128 split-precision MFMA GEMM (N<=1536 GEMMs) + XCD swizzle.
// =====================================================================
template<int MODE, int RELU, int HAS_BIAS>
__global__ __launch_bounds__(256)
void mgemm_k(const unsigned short* __restrict__ Ah, const unsigned short* __restrict__ Al,
             const unsigned short* __restrict__ Bh, const unsigned short* __restrict__ Bl,
             const float* __restrict__ bias, float* __restrict__ C,
             unsigned short* __restrict__ Ch, unsigned short* __restrict__ Cl,
             int M, int N, int K, float alpha)
{
    __shared__ uint4 smem_u4[4096];
    unsigned char* smem = (unsigned char*)smem_u4;
    const int tid  = threadIdx.x;
    const int lane = tid & 63;
    const int w    = tid >> 6;
    const int gx = gridDim.x;
    int bid = blockIdx.y * gx + blockIdx.x;
    const int nwg = gx * gridDim.y;
    bid = (bid & 7) * (nwg >> 3) + (bid >> 3);
    const int bxs = bid % gx, bys = bid / gx;
    const int brow = bys * 128;
    const int bcol = bxs * 128;
    const int wr = (w >> 1) * 64, wc = (w & 1) * 64;
    const size_t Kb = (size_t)K * 2;

    const unsigned short* srcM; int rb;
    if      (w == 0) { srcM = Ah; rb = brow; }
    else if (w == 1) { srcM = Al; rb = brow; }
    else if (w == 2) { srcM = Bh; rb = bcol; }
    else             { srcM = Bl; rb = bcol; }
    const int swzsrc = (((lane & 7) << 4) ^ (((lane >> 3) & 7) << 4));
    const unsigned char* srow = (const unsigned char*)srcM
                              + (size_t)(rb + (lane >> 3)) * Kb + swzsrc;
    unsigned char* dbase = smem + w * 16384;

    const int lm = lane & 15;
    const int lg = lane >> 4;
    const int lswz = (lane & 7);

    f32x4 acc[4][4];
#pragma unroll
    for (int i = 0; i < 4; ++i)
#pragma unroll
        for (int j = 0; j < 4; ++j) acc[i][j] = (f32x4)(0.f);

    for (int k0 = 0; k0 < K; k0 += 64) {
#pragma unroll
        for (int j = 0; j < 16; ++j) {
            const unsigned char* sp = srow + (size_t)(j * 8) * Kb + (size_t)k0 * 2;
            __builtin_amdgcn_global_load_lds(
                (const __attribute__((address_space(1))) unsigned int*)sp,
                (__attribute__((address_space(3))) unsigned int*)(dbase + j * 1024),
                16, 0, 0);
        }
        __syncthreads();
#pragma unroll
        for (int ks = 0; ks < 2; ++ks) {
            const int kf = (((ks << 2) + lg) ^ lswz) << 4;
            bf16x8 bh[4], bl[4];
#pragma unroll
            for (int n = 0; n < 4; ++n) {
                const int r = wc + n * 16 + lm;
                bh[n] = *(const bf16x8*)(smem + 32768 + r * 128 + kf);
                bl[n] = *(const bf16x8*)(smem + 49152 + r * 128 + kf);
            }
#pragma unroll
            for (int m = 0; m < 4; ++m) {
                const int r = wr + m * 16 + lm;
                bf16x8 ah = *(const bf16x8*)(smem +         r * 128 + kf);
                bf16x8 al = *(const bf16x8*)(smem + 16384 + r * 128 + kf);
#pragma unroll
                for (int n = 0; n < 4; ++n) {
                    acc[m][n] = __builtin_amdgcn_mfma_f32_16x16x32_bf16(al, bh[n], acc[m][n], 0, 0, 0);
                    acc[m][n] = __builtin_amdgcn_mfma_f32_16x16x32_bf16(ah, bl[n], acc[m][n], 0, 0, 0);
                    acc[m][n] = __builtin_amdgcn_mfma_f32_16x16x32_bf16(ah, bh[n], acc[m][n], 0, 0, 0);
                }
            }
        }
        __syncthreads();
    }

#pragma unroll
    for (int n = 0; n < 4; ++n) {
        const int colg = bcol + wc + n * 16 + lm;
        const float bv = HAS_BIAS ? bias[colg] : 0.f;
#pragma unroll
        for (int m = 0; m < 4; ++m) {
            const int rowb = brow + wr + m * 16 + lg * 4;
#pragma unroll
            for (int r = 0; r < 4; ++r) {
                float v = alpha * acc[m][n][r] + bv;
                if (RELU) v = fmaxf(v, 0.f);
                if (MODE == 0) {
                    C[(size_t)(rowb + r) * N + colg] = v;
                } else {
                    unsigned short h, l;
                    split2(v, h, l);
                    Ch[(size_t)(rowb + r) * N + colg] = h;
                    Cl[(size_t)(rowb + r) * N + colg] = l;
                }
            }
        }
    }
}

// ---------------------------------------------- weight transpose + split
__global__ __launch_bounds__(256)
void tsplit_k(const float* __restrict__ W, unsigned short* __restrict__ TH,
              unsigned short* __restrict__ TL, int K, int N)
{
    __shared__ float t[32][33];
    const int tid = threadIdx.x;
    const int n0 = blockIdx.x * 32, k0 = blockIdx.y * 32;
    {
        const int r = tid >> 3, c = (tid & 7) * 4;
        const float4 v = *(const float4*)(W + (size_t)(k0 + r) * N + n0 + c);
        t[r][c] = v.x; t[r][c + 1] = v.y; t[r][c + 2] = v.z; t[r][c + 3] = v.w;
    }
    __syncthreads();
    const int rn = tid >> 3, ck = (tid & 7) * 4;
    unsigned short h[4], l[4];
#pragma unroll
    for (int i = 0; i < 4; ++i) split2(t[ck + i][rn], h[i], l[i]);
    *(ushort4*)(TH + (size_t)(n0 + rn) * K + k0 + ck) = make_ushort4(h[0], h[1], h[2], h[3]);
    *(ushort4*)(TL + (size_t)(n0 + rn) * K + k0 + ck) = make_ushort4(l[0], l[1], l[2], l[3]);
}

// ---------------------------------------------------------- split fp32 -> planes
__global__ __launch_bounds__(256)
void split_k(const float* __restrict__ in, unsigned short* __restrict__ hi,
             unsigned short* __restrict__ lo, int n4)
{
    int i = blockIdx.x * 256 + threadIdx.x;
    const int stride = gridDim.x * 256;
    for (; i < n4; i += stride) {
        const float4 v = *(const float4*)(in + (size_t)i * 4);
        unsigned short h[4], l[4];
        split2(v.x, h[0], l[0]); split2(v.y, h[1], l[1]);
        split2(v.z, h[2], l[2]); split2(v.w, h[3], l[3]);
        *(ushort4*)(hi + (size_t)i * 4) = make_ushort4(h[0], h[1], h[2], h[3]);
        *(ushort4*)(lo + (size_t)i * 4) = make_ushort4(l[0], l[1], l[2], l[3]);
    }
}

// ----------------------------------------------- causal flash attention (fp32)
// Reads fused QKV [kN][1536] (Q|K|V of 512 each); q scaled 0.125 on load.
// Writes O directly as bf16 hi/lo planes [kN][512].
__global__ __launch_bounds__(256)
void attn_k(const float* __restrict__ QKV,
            unsigned short* __restrict__ OH, unsigned short* __restrict__ OL)
{
    __shared__ float Qs[64][68];
    __shared__ float Ks[64][68];
    __shared__ float Vs[64][68];
    __shared__ float Ps[64][68];
    const int tid = threadIdx.x;
    const int tr = tid >> 4, tc = tid & 15;
    const int qt = blockIdx.x & 15;
    const int h  = (blockIdx.x >> 4) & 7;
    const int b  = blockIdx.x >> 7;
    const int q0 = qt * 64;
    const float* Qb = QKV + ((size_t)(b * kS + q0)) * kLQ + h * kHD;
    {
        const int r = tid >> 2;
#pragma unroll
        for (int it = 0; it < 4; ++it) {
            const int e0 = ((tid & 3) << 2) + it * 16;
            const float4 q4 = *(const float4*)(Qb + (size_t)r * kLQ + e0);
            Qs[e0 + 0][r] = q4.x * 0.125f; Qs[e0 + 1][r] = q4.y * 0.125f;
            Qs[e0 + 2][r] = q4.z * 0.125f; Qs[e0 + 3][r] = q4.w * 0.125f;
        }
    }
    float m[4], l[4], acc[4][4];
#pragma unroll
    for (int i = 0; i < 4; ++i) {
        m[i] = -INFINITY; l[i] = 0.f;
#pragma unroll
        for (int j = 0; j < 4; ++j) acc[i][j] = 0.f;
    }
    for (int j0 = 0; j0 <= q0; j0 += 64) {
        const float* Kb = QKV + ((size_t)(b * kS + j0)) * kLQ + 512 + h * kHD;
        const float* Vb = QKV + ((size_t)(b * kS + j0)) * kLQ + 1024 + h * kHD;
        __syncthreads();
        {
            const int c = tid >> 2;
#pragma unroll
            for (int it = 0; it < 4; ++it) {
                const int e0 = ((tid & 3) << 2) + it * 16;
                const float4 k4 = *(const float4*)(Kb + (size_t)c * kLQ + e0);
                Ks[e0 + 0][c] = k4.x; Ks[e0 + 1][c] = k4.y;
                Ks[e0 + 2][c] = k4.z; Ks[e0 + 3][c] = k4.w;
                *(float4*)&Vs[c][e0] = *(const float4*)(Vb + (size_t)c * kLQ + e0);
            }
        }
        __syncthreads();
        float s[4][4];
#pragma unroll
        for (int i = 0; i < 4; ++i)
#pragma unroll
            for (int j = 0; j < 4; ++j) s[i][j] = 0.f;
        for (int e = 0; e < 64; ++e) {
            float qa[4], kb[4];
            *(float4*)&qa[0] = *(const float4*)&Qs[e][tr * 4];
            *(float4*)&kb[0] = *(const float4*)&Ks[e][tc * 4];
#pragma unroll
            for (int i = 0; i < 4; ++i)
#pragma unroll
                for (int j = 0; j < 4; ++j)
                    s[i][j] = fmaf(qa[i], kb[j], s[i][j]);
        }
        if (j0 == q0) {
#pragma unroll
            for (int i = 0; i < 4; ++i)
#pragma unroll
                for (int j = 0; j < 4; ++j)
                    if (tc * 4 + j > tr * 4 + i) s[i][j] = -INFINITY;
        }
#pragma unroll
        for (int i = 0; i < 4; ++i) {
            float rm = fmaxf(fmaxf(s[i][0], s[i][1]), fmaxf(s[i][2], s[i][3]));
            rm = fmaxf(rm, __shfl_xor(rm, 1));
            rm = fmaxf(rm, __shfl_xor(rm, 2));
            rm = fmaxf(rm, __shfl_xor(rm, 4));
            rm = fmaxf(rm, __shfl_xor(rm, 8));
            const float mn = fmaxf(m[i], rm);
            const float co = expf(m[i] - mn);
            float ps = 0.f;
#pragma unroll
            for (int j = 0; j < 4; ++j) { s[i][j] = expf(s[i][j] - mn); ps += s[i][j]; }
            ps += __shfl_xor(ps, 1); ps += __shfl_xor(ps, 2);
            ps += __shfl_xor(ps, 4); ps += __shfl_xor(ps, 8);
            l[i] = l[i] * co + ps;
            m[i] = mn;
#pragma unroll
            for (int j = 0; j < 4; ++j) acc[i][j] *= co;
            *(float4*)&Ps[tr * 4 + i][tc * 4] = make_float4(s[i][0], s[i][1], s[i][2], s[i][3]);
        }
        __syncthreads();
        for (int c = 0; c < 64; ++c) {
            const float4 v4 = *(const float4*)&Vs[c][tc * 4];
#pragma unroll
            for (int i = 0; i < 4; ++i) {
                const float p = Ps[tr * 4 + i][c];
                acc[i][0] = fmaf(p, v4.x, acc[i][0]);
                acc[i][1] = fmaf(p, v4.y, acc[i][1]);
                acc[i][2] = fmaf(p, v4.z, acc[i][2]);
                acc[i][3] = fmaf(p, v4.w, acc[i][3]);
            }
        }
    }
    const size_t ob = ((size_t)(b * kS + q0)) * kD + h * kHD;
#pragma unroll
    for (int i = 0; i < 4; ++i) {
        const float inv = 1.0f / l[i];
        unsigned short hh[4], ll[4];
#pragma unroll
        for (int j = 0; j < 4; ++j) split2(acc[i][j] * inv, hh[j], ll[j]);
        const size_t off = ob + (size_t)(tr * 4 + i) * kD + tc * 4;
        *(ushort4*)(OH + off) = make_ushort4(hh[0], hh[1], hh[2], hh[3]);
        *(ushort4*)(OL + off) = make_ushort4(ll[0], ll[1], ll[2], ll[3]);
    }
}

// ---------------------------------------------------------- LayerNorm (+planes)
__global__ __launch_bounds__(256)
void ln_k(const float* __restrict__ a, const float* __restrict__ b,
          const float* __restrict__ sc, const float* __restrict__ bi,
          float* __restrict__ out, unsigned short* __restrict__ oh,
          unsigned short* __restrict__ ol)
{
    const int w = threadIdx.x >> 6, lane = threadIdx.x & 63;
    const size_t row = (size_t)blockIdx.x * 4 + w;
    const float* ap = a + row * kD;
    float x[8];
    *(float4*)&x[0] = *(const float4*)(ap + lane * 8);
    *(float4*)&x[4] = *(const float4*)(ap + lane * 8 + 4);
    if (b) {
        const float* bp = b + row * kD;
        float y[8];
        *(float4*)&y[0] = *(const float4*)(bp + lane * 8);
        *(float4*)&y[4] = *(const float4*)(bp + lane * 8 + 4);
#pragma unroll
        for (int k = 0; k < 8; ++k) x[k] += y[k];
    }
    float s = 0.f;
#pragma unroll
    for (int k = 0; k < 8; ++k) s += x[k];
    for (int msk = 1; msk < 64; msk <<= 1) s += __shfl_xor(s, msk);
    const float mean = s * (1.0f / 512.0f);
    float v = 0.f;
#pragma unroll
    for (int k = 0; k < 8; ++k) { const float d = x[k] - mean; v = fmaf(d, d, v); }
    for (int msk = 1; msk < 64; msk <<= 1) v += __shfl_xor(v, msk);
    const float rstd = 1.0f / sqrtf(v * (1.0f / 512.0f) + 1e-6f);
    float o[8]; unsigned short h[8], lo2[8];
#pragma unroll
    for (int k = 0; k < 8; ++k) {
        const int col = lane * 8 + k;
        o[k] = (x[k] - mean) * rstd * sc[col] + bi[col];
        split2(o[k], h[k], lo2[k]);
    }
    *(float4*)(out + row * kD + lane * 8)     = *(const float4*)&o[0];
    *(float4*)(out + row * kD + lane * 8 + 4) = *(const float4*)&o[4];
    *(ushort4*)(oh + row * kD + lane * 8)     = make_ushort4(h[0], h[1], h[2], h[3]);
    *(ushort4*)(oh + row * kD + lane * 8 + 4) = make_ushort4(h[4], h[5], h[6], h[7]);
    *(ushort4*)(ol + row * kD + lane * 8)     = make_ushort4(lo2[0], lo2[1], lo2[2], lo2[3]);
    *(ushort4*)(ol + row * kD + lane * 8 + 4) = make_ushort4(lo2[4], lo2[5], lo2[6], lo2[7]);
}

// ---------------------------------------------------------- row softmax (+planes)
__global__ __launch_bounds__(256)
void softmax_k(const float* __restrict__ in, float* __restrict__ out,
               unsigned short* __restrict__ oh, unsigned short* __restrict__ ol)
{
    const int w = threadIdx.x >> 6, lane = threadIdx.x & 63;
    const size_t row = (size_t)blockIdx.x * 4 + w;
    const float* ip = in + row * kD;
    float x[8];
    *(float4*)&x[0] = *(const float4*)(ip + lane * 8);
    *(float4*)&x[4] = *(const float4*)(ip + lane * 8 + 4);
    float mx = x[0];
#pragma unroll
    for (int k = 1; k < 8; ++k) mx = fmaxf(mx, x[k]);
    for (int msk = 1; msk < 64; msk <<= 1) mx = fmaxf(mx, __shfl_xor(mx, msk));
    float s = 0.f;
#pragma unroll
    for (int k = 0; k < 8; ++k) { x[k] = expf(x[k] - mx); s += x[k]; }
    for (int msk = 1; msk < 64; msk <<= 1) s += __shfl_xor(s, msk);
    const float inv = 1.0f / s;
    unsigned short h[8], lo2[8];
#pragma unroll
    for (int k = 0; k < 8; ++k) { x[k] *= inv; split2(x[k], h[k], lo2[k]); }
    *(float4*)(out + row * kD + lane * 8)     = *(const float4*)&x[0];
    *(float4*)(out + row * kD + lane * 8 + 4) = *(const float4*)&x[4];
    *(ushort4*)(oh + row * kD + lane * 8)     = make_ushort4(h[0], h[1], h[2], h[3]);
    *(ushort4*)(oh + row * kD + lane * 8 + 4) = make_ushort4(h[4], h[5], h[6], h[7]);
    *(ushort4*)(ol + row * kD + lane * 8)     = make_ushort4(lo2[0], lo2[1], lo2[2], lo2[3]);
    *(ushort4*)(ol + row * kD + lane * 8 + 4) = make_ushort4(lo2[4], lo2[5], lo2[6], lo2[7]);
}

// ---------------------------------------------------------- ||x_row||
__global__ __launch_bounds__(256)
void xnorm_k(const float* __restrict__ X, float* __restrict__ XN)
{
    const int tid = threadIdx.x;
    const int row = blockIdx.x * 8 + (tid >> 5);
    const int o = tid & 31;
    const float v = X[(size_t)row * kOUT + o];
    float s = v * v;
    s += __shfl_xor(s, 1); s += __shfl_xor(s, 2); s += __shfl_xor(s, 4);
    s += __shfl_xor(s, 8); s += __shfl_xor(s, 16);
    if (o == 0) XN[row] = sqrtf(s);
}

// ------------------------------------- argmax + gather winning slot column
__global__ __launch_bounds__(256)
void pick_k(const float* __restrict__ scores, const float* __restrict__ keys,
            const float* __restrict__ Wvs, const float* __restrict__ bvs,
            const float* __restrict__ Ss, float* __restrict__ vout,
            float* __restrict__ sout)
{
    const int n = blockIdx.x;
    const int tid = threadIdx.x;
    __shared__ float sv[256];
    __shared__ int   si[256];
    __shared__ float ks[512];
    __shared__ float red[256];
    const float s0 = scores[(size_t)n * kSL + tid];
    const float s1 = scores[(size_t)n * kSL + tid + 256];
    float bs; int bi;
    if (s1 > s0) { bs = s1; bi = tid + 256; } else { bs = s0; bi = tid; }
    sv[tid] = bs; si[tid] = bi;
    ks[tid] = keys[(size_t)n * kD + tid];
    ks[tid + 256] = keys[(size_t)n * kD + tid + 256];
    __syncthreads();
    for (int off = 128; off > 0; off >>= 1) {
        if (tid < off) {
            const float ov = sv[tid + off]; const int oi = si[tid + off];
            if (ov > sv[tid] || (ov == sv[tid] && oi < si[tid])) { sv[tid] = ov; si[tid] = oi; }
        }
        __syncthreads();
    }
    const int idx = si[0];
    const int o = tid & 31;
    const int seg = tid >> 5;
    const float* Wc = Wvs + (size_t)idx * kOUT + o;
    float part = 0.f;
    for (int d = seg * 64; d < seg * 64 + 64; ++d)
        part = fmaf(ks[d], Wc[(size_t)d * (kSL * kOUT)], part);
    red[tid] = part;
    __syncthreads();
    if (tid < 32) {
        float t = red[tid];
#pragma unroll
        for (int ss = 1; ss < 8; ++ss) t += red[tid + 32 * ss];
        vout[(size_t)n * kOUT + tid] = t + bvs[idx * kOUT + tid];
    }
    if (tid == 0) sout[n] = Ss[(size_t)n * kSL + idx];
}

// ------------------------------------------------------------------ host
extern "C" void kernel_launch(void* const* d_in, const int* in_sizes, int n_in,
                              void* d_out, int out_size, void* d_ws, size_t ws_size,
                              hipStream_t stream)
{
    (void)in_sizes; (void)n_in; (void)out_size; (void)ws_size;
    const float* s_in = (const float*)d_in[0];
    const float* x_in = (const float*)d_in[1];
    const float* t_in = (const float*)d_in[2];
    const float* Wq   = (const float*)d_in[3];
    const float* Wk   = (const float*)d_in[4];
    const float* Wv   = (const float*)d_in[5];
    const float* Wo   = (const float*)d_in[6];
    const float* cWv  = (const float*)d_in[9];
    const float* cWo  = (const float*)d_in[10];
    const float* ln1s = (const float*)d_in[11];
    const float* ln1b = (const float*)d_in[12];
    const float* ln2s = (const float*)d_in[13];
    const float* ln2b = (const float*)d_in[14];
    const float* ln3s = (const float*)d_in[15];
    const float* ln3b = (const float*)d_in[16];
    const float* W1   = (const float*)d_in[17];
    const float* b1   = (const float*)d_in[18];
    const float* W2   = (const float*)d_in[19];
    const float* b2   = (const float*)d_in[20];
    const float* lnfs = (const float*)d_in[21];
    const float* lnfb = (const float*)d_in[22];
    const float* Wout = (const float*)d_in[23];
    const float* bout = (const float*)d_in[24];
    const float* Wvs  = (const float*)d_in[25];
    const float* bvs  = (const float*)d_in[26];
    const float* Wss  = (const float*)d_in[27];
    const float* bss  = (const float*)d_in[28];

    float* out_v  = (float*)d_out;
    float* out_s  = out_v + (size_t)kN * kOUT;
    float* out_Ss = out_s + kN;

    unsigned char* w8 = (unsigned char*)d_ws;
    const size_t MD = (size_t)kN * kD;
    float* f_dec = (float*)w8;
    float* f_A   = f_dec + MD;          // f_A..f_C contiguous = fused QKV [kN][1536]
    float* f_B   = f_A + MD;
    float* f_C   = f_B + MD;
    float* f_xn  = f_C + MD;
    unsigned short* dH = (unsigned short*)(f_xn + kN);
    unsigned short* dL = dH + MD;
    unsigned short* hH = dL + MD;                       // [kN][kFF]
    unsigned short* hL = hH + (size_t)kN * kFF;
    unsigned short* wTH = hL + (size_t)kN * kFF;        // [<=16384][<=2048]
    unsigned short* wTL = wTH + (size_t)kSL * kOUT * kD;
    float* f_qkv = f_A;
    unsigned short* sH = hH;            // attn-out / t_in planes
    unsigned short* sL = hL;
    unsigned short* kH = hH;            // keys planes (end stage, hH free)
    unsigned short* kL = hL;

    const dim3 blk(256);
    const dim3 blk512(512);
    const size_t DD = (size_t)kD * kD;

    auto tsplit = [&](const float* W, int Kd, int Nd, unsigned short* TH, unsigned short* TL) {
        tsplit_k<<<dim3(Nd / 32, Kd / 32), blk, 0, stream>>>(W, TH, TL, Kd, Nd);
    };

    xnorm_k<<<kN / 8, blk, 0, stream>>>(x_in, f_xn);
    split_k<<<1024, blk, 0, stream>>>(s_in, dH, dL, (int)(MD / 4));

    const float* cur = s_in;
    for (int l = 0; l < 2; ++l) {
        const size_t wo = (size_t)l * DD;
        // fused QKV projection (N=1536); q-scale folded into attn
        tsplit(Wq + wo, kD, kD, wTH,             wTL);
        tsplit(Wk + wo, kD, kD, wTH + 512 * kD,  wTL + 512 * kD);
        tsplit(Wv + wo, kD, kD, wTH + 1024 * kD, wTL + 1024 * kD);
        mgemm_k<0, 0, 0><<<dim3(kLQ / 128, kN / 128), blk, 0, stream>>>(
            dH, dL, wTH, wTL, nullptr, f_qkv, nullptr, nullptr, kN, kLQ, kD, 1.f);
        attn_k<<<1024, blk, 0, stream>>>(f_qkv, sH, sL);
        tsplit(Wo + wo, kD, kD, wTH, wTL);
        mgemm_k<0, 0, 0><<<dim3(4, 64), blk, 0, stream>>>(
            sH, sL, wTH, wTL, nullptr, f_A, nullptr, nullptr, kN, kD, kD, 1.f);
        ln_k<<<kN / 4, blk, 0, stream>>>(cur, f_A, ln1s + l * kD, ln1b + l * kD, f_dec, dH, dL);
        // cross-attention (eye mask) == (t @ cWv) @ cWo
        split_k<<<1024, blk, 0, stream>>>(t_in, sH, sL, (int)(MD / 4));
        tsplit(cWv + wo, kD, kD, wTH, wTL);
        mgemm_k<1, 0, 0><<<dim3(4, 64), blk, 0, stream>>>(
            sH, sL, wTH, wTL, nullptr, nullptr, dH, dL, kN, kD, kD, 1.f);
        tsplit(cWo + wo, kD, kD, wTH, wTL);
        mgemm_k<0, 0, 0><<<dim3(4, 64), blk, 0, stream>>>(
            dH, dL, wTH, wTL, nullptr, f_A, nullptr, nullptr, kN, kD, kD, 1.f);
        ln_k<<<kN / 4, blk, 0, stream>>>(f_dec, f_A, ln2s + l * kD, ln2b + l * kD, f_dec, dH, dL);
        // FFN
        tsplit(W1 + (size_t)l * kD * kFF, kD, kFF, wTH, wTL);
        mgemm256_k<1, 1, 1><<<dim3(kFF / 256, kN / 256), blk512, 0, stream>>>(
            dH, dL, wTH, wTL, b1 + (size_t)l * kFF, nullptr, hH, hL,
            nullptr, nullptr, nullptr, kN, kFF, kD, 1.f);
        tsplit(W2 + (size_t)l * kFF * kD, kFF, kD, wTH, wTL);
        mgemm_k<0, 0, 1><<<dim3(4, 64), blk, 0, stream>>>(
            hH, hL, wTH, wTL, b2 + (size_t)l * kD, f_A, nullptr, nullptr, kN, kD, kFF, 1.f);
        ln_k<<<kN / 4, blk, 0, stream>>>(f_dec, f_A, ln3s + l * kD, ln3b + l * kD, f_dec, dH, dL);
        cur = f_dec;
    }
    // final LN -> logits -> keys
    ln_k<<<kN / 4, blk, 0, stream>>>(f_dec, nullptr, lnfs, lnfb, f_A, dH, dL);
    tsplit(Wout, kD, kD, wTH, wTL);
    mgemm_k<0, 0, 1><<<dim3(4, 64), blk, 0, stream>>>(
        dH, dL, wTH, wTL, bout, f_B, nullptr, nullptr, kN, kD, kD, 1.f);
    softmax_k<<<kN / 4, blk, 0, stream>>>(f_B, f_C, kH, kL);   // keys fp32 in f_C
    // Ss
    tsplit(Wss, kD, kSL, wTH, wTL);
    mgemm_k<0, 0, 1><<<dim3(4, 64), blk, 0, stream>>>(
        kH, kL, wTH, wTL, bss, out_Ss, nullptr, nullptr, kN, kSL, kD, 1.f);
    // fused cosine scoring -> f_B
    tsplit(Wvs, kD, kSL * kOUT, wTH, wTL);
    mgemm256_k<2, 0, 1><<<dim3(kSL * kOUT / 256, kN / 256), blk512, 0, stream>>>(
        kH, kL, wTH, wTL, bvs, nullptr, nullptr, nullptr, x_in, f_xn, f_B,
        kN, kSL * kOUT, kD, 1.f);
    pick_k<<<kN, blk, 0, stream>>>(f_B, f_C, Wvs, bvs, out_Ss, out_v, out_s);
}